// Round 3
// baseline (170.661 us; speedup 1.0000x reference)
//
#include <hip/hip_runtime.h>
#include <hip/hip_bf16.h>

// TDCPQueryAttentionPool fused kernel for MI355X (gfx950).
// B=8, N=4096, M=4, E=512, H=8, d=64. tokens = 32768.
//
// R3: occupancy push. 1024-thread blocks (16 waves), each wave owns ONE
// 32-col tile -> acc[4] (64 VGPR). B-frags single-buffered (4/step), x
// 3-deep prefetch in 2 reg banks. __launch_bounds__(1024,4) forces <=128
// regs -> 4 waves/SIMD. Counted-vmcnt pipeline, raw barriers, cvt_pk pack.

typedef float  f32x4  __attribute__((ext_vector_type(4)));
typedef float  f32x16 __attribute__((ext_vector_type(16)));
typedef short  short8 __attribute__((ext_vector_type(8)));

__device__ __forceinline__ unsigned short f2bf(float f) {
  unsigned int x = __float_as_uint(f);
  unsigned int r = (x + 0x7fffu + ((x >> 16) & 1u)) >> 16;  // RNE
  return (unsigned short)r;
}

__device__ __forceinline__ short8 pack8(const f32x4& a, const f32x4& b) {
  unsigned int r0, r1, r2, r3;
  asm("v_cvt_pk_bf16_f32 %0, %1, %2" : "=v"(r0) : "v"(a[0]), "v"(a[1]));
  asm("v_cvt_pk_bf16_f32 %0, %1, %2" : "=v"(r1) : "v"(a[2]), "v"(a[3]));
  asm("v_cvt_pk_bf16_f32 %0, %1, %2" : "=v"(r2) : "v"(b[0]), "v"(b[1]));
  asm("v_cvt_pk_bf16_f32 %0, %1, %2" : "=v"(r3) : "v"(b[2]), "v"(b[3]));
  short8 r;
  r[0] = (short)(r0 & 0xffff); r[1] = (short)(r0 >> 16);
  r[2] = (short)(r1 & 0xffff); r[3] = (short)(r1 >> 16);
  r[4] = (short)(r2 & 0xffff); r[5] = (short)(r2 >> 16);
  r[6] = (short)(r3 & 0xffff); r[7] = (short)(r3 >> 16);
  return r;
}

__device__ __forceinline__ void mfma32(f32x16& c, short8 a, short8 b) {
  asm("v_mfma_f32_32x32x16_bf16 %0, %1, %2, %0" : "+v"(c) : "v"(a), "v"(b));
}
__device__ __forceinline__ void mfma16(f32x4& c, short8 a, short8 b) {
  asm("v_mfma_f32_16x16x32_bf16 %0, %1, %2, %0" : "+v"(c) : "v"(a), "v"(b));
}

__device__ __forceinline__ void gld4f(f32x4& d, const float* p) {
  asm volatile("global_load_dwordx4 %0, %1, off" : "=v"(d) : "v"(p));
}
__device__ __forceinline__ void gld4s(short8& d, const unsigned short* p) {
  asm volatile("global_load_dwordx4 %0, %1, off" : "=v"(d) : "v"(p));
}

__device__ __forceinline__ void wxv2(f32x4& a, f32x4& b) {
  asm volatile("s_waitcnt vmcnt(2)" : "+v"(a), "+v"(b));
}
__device__ __forceinline__ void wxv4(f32x4& a, f32x4& b) {
  asm volatile("s_waitcnt vmcnt(4)" : "+v"(a), "+v"(b));
}
__device__ __forceinline__ void wxv6(f32x4& a, f32x4& b) {
  asm volatile("s_waitcnt vmcnt(6)" : "+v"(a), "+v"(b));
}
__device__ __forceinline__ void wbv2(short8& a, short8& b, short8& c, short8& d) {
  asm volatile("s_waitcnt vmcnt(2)" : "+v"(a), "+v"(b), "+v"(c), "+v"(d));
}
__device__ __forceinline__ void wbv0(short8& a, short8& b, short8& c, short8& d) {
  asm volatile("s_waitcnt vmcnt(0)" : "+v"(a), "+v"(b), "+v"(c), "+v"(d));
}

// ---------------------------------------------------------------------------
// K0: precompute (unchanged; correctness-verified).
// ---------------------------------------------------------------------------
__global__ void __launch_bounds__(512) tdcp_k0(
    const float* __restrict__ q_param, const float* __restrict__ in_w,
    const float* __restrict__ in_b, const float* __restrict__ out_w,
    float* __restrict__ scoreb, unsigned short* __restrict__ wscB,
    unsigned short* __restrict__ WvB, unsigned short* __restrict__ WoB)
{
  const int tid = threadIdx.x;
  const int blk = blockIdx.x;
  if (blk < 8) {
    const int h = blk;
    __shared__ float qls[512];
    __shared__ float qs[64];
    qls[tid] = q_param[tid];
    __syncthreads();
    {
      const int io = tid >> 3, sub = tid & 7;
      const float* wrow = in_w + (size_t)(h * 64 + io) * 512;
      float v = 0.f;
      #pragma unroll 8
      for (int ee = 0; ee < 64; ++ee) {
        const int e = sub + (ee << 3);
        v += wrow[e] * qls[e];
      }
      v += __shfl_xor(v, 1); v += __shfl_xor(v, 2); v += __shfl_xor(v, 4);
      if (sub == 0) qs[io] = (v + in_b[h * 64 + io]) * 0.125f;
    }
    __syncthreads();
    {
      const int e = tid;
      const float* wk = in_w + (size_t)(512 + h * 64) * 512 + e;
      float v = 0.f;
      #pragma unroll 8
      for (int jj = 0; jj < 64; ++jj) v += qs[jj] * wk[jj * 512];
      const int s32 = e >> 5, g = (e & 31) >> 3, j = e & 7;
      wscB[((s32 << 6) + h + (g << 4)) * 8 + j] = f2bf(v);
      wscB[((s32 << 6) + (h + 8) + (g << 4)) * 8 + j] = 0;
    }
    if (tid < 64) {
      float v = qs[tid] * in_b[512 + h * 64 + tid];
      v += __shfl_xor(v, 1);  v += __shfl_xor(v, 2);  v += __shfl_xor(v, 4);
      v += __shfl_xor(v, 8);  v += __shfl_xor(v, 16); v += __shfl_xor(v, 32);
      if (tid == 0) scoreb[h] = v;
    }
    if (blk == 0 && tid >= 64 && tid < 72) scoreb[tid - 56] = 0.f;
  } else {
    const int mb = blk - 8;
    const bool isWo = mb >= 64;
    const float* src = isWo ? out_w : (in_w + (size_t)1024 * 512);
    unsigned short* dst = isWo ? WoB : WvB;
    const int slot = ((mb & 63) << 9) + tid;
    const int ct = slot >> 11, kt = (slot >> 6) & 31, ln = slot & 63;
    const float* p = src + (size_t)(ct * 32 + (ln & 31)) * 512
                         + kt * 16 + ((ln >> 5) << 3);
    const f32x4 u0 = *(const f32x4*)(p);
    const f32x4 u1 = *(const f32x4*)(p + 4);
    unsigned int r0, r1, r2, r3;
    short8 rr;
    rr[0] = (short)f2bf(u0[0]); rr[1] = (short)f2bf(u0[1]);
    rr[2] = (short)f2bf(u0[2]); rr[3] = (short)f2bf(u0[3]);
    rr[4] = (short)f2bf(u1[0]); rr[5] = (short)f2bf(u1[1]);
    rr[6] = (short)f2bf(u1[2]); rr[7] = (short)f2bf(u1[3]);
    *(short8*)(dst + slot * 8) = rr;
    (void)r0; (void)r1; (void)r2; (void)r3;
  }
}

// ---------------------------------------------------------------------------
// K1: fused attention-pool, 16 waves/block, counted-vmcnt pipeline.
// LDS: [0,48K) three 16K x-buffers; [48K,64K) wsc frags.
// Epilogue reuse: omid [0,32K), av [32K,36K), stats [36K,40K).
// ---------------------------------------------------------------------------
__global__ void __launch_bounds__(1024, 4) tdcp_k1(
    const float* __restrict__ f0, const float* __restrict__ f1,
    const float* __restrict__ f2, const float* __restrict__ f3,
    const float* __restrict__ in_b,
    const float* __restrict__ scoreb, const unsigned short* __restrict__ wscB,
    const unsigned short* __restrict__ WvB, const unsigned short* __restrict__ WoB,
    const float* __restrict__ out_b, const float* __restrict__ gamma,
    const float* __restrict__ beta, float* __restrict__ out)
{
  __shared__ __align__(16) char smem[65536];
  const int tid = threadIdx.x;
  const int w = tid >> 6;         // wave 0..15: owns output cols [32w,32w+32)
  const int l = tid & 63;
  const int tok0 = blockIdx.x << 5;

  // ---- wsc -> LDS (16 KB) ----
  {
    const f32x4* wsrc = (const f32x4*)wscB;
    f32x4* wdst = (f32x4*)(smem + 49152);
    wdst[tid] = wsrc[tid];
  }

  // ---- staging map: row sr = t*4+m (0..127); 8 floats per thread/step ----
  const int sr = tid >> 3;
  const int c16 = (tid & 7) >> 1;           // 16-float chunk 0..3
  const int half = tid & 1;
  const int sm = sr & 3;
  const int stk = sr >> 2;
  const float* fsrc = (sm == 0 ? f0 : sm == 1 ? f1 : sm == 2 ? f2 : f3)
                      + (size_t)(tok0 + stk) * 512 + ((tid & 7) << 3);
  const int wbase = (c16 << 12) + ((sr >> 5) << 10)
                  + (((sr & 31) << 4) ^ (c16 << 5)) + (half << 9);

  // ---- fragment-read bases ----
  const int aO = ((l >> 5) << 9) + ((l & 31) << 4);
  const int sBase = ((w >> 1) << 10) + (((l >> 4) & 1) << 9)
                  + ((((w & 1) << 4) | (l & 15)) << 4);
  const unsigned short* wv = WvB + (((w * 32) << 6) + l) * 8;
  const unsigned short* wo = WoB + (((w * 32) << 6) + l) * 8;
  const unsigned short* wscL = (const unsigned short*)(smem + 49152);

  f32x16 acc[4];
  f32x4 sacc;
  #pragma unroll
  for (int i = 0; i < 4; ++i)
    #pragma unroll
    for (int r = 0; r < 16; ++r) acc[i][r] = 0.f;
  sacc[0] = sacc[1] = sacc[2] = sacc[3] = 0.f;

  f32x4 lx[2][2];
  short8 bb[4];

  // ---- prologue ----
  gld4f(lx[0][0], fsrc);      gld4f(lx[0][1], fsrc + 4);
  gld4f(lx[1][0], fsrc + 64); gld4f(lx[1][1], fsrc + 68);
  wxv2(lx[0][0], lx[0][1]);
  *(short8*)(smem + wbase) = pack8(lx[0][0], lx[0][1]);
  #pragma unroll
  for (int j = 0; j < 4; ++j) gld4s(bb[j], wv + j * 512);
  gld4f(lx[0][0], fsrc + 128); gld4f(lx[0][1], fsrc + 132);
  asm volatile("s_waitcnt lgkmcnt(0)" ::: "memory");
  __builtin_amdgcn_s_barrier();
  asm volatile("" ::: "memory");

  // ---- main loop: 8 steps of 64 e-elements ----
  #pragma unroll
  for (int s = 0; s < 8; ++s) {
    if (s < 7) {
      f32x4 (&L)[2] = lx[(s + 1) & 1];
      if (s < 6) wxv6(L[0], L[1]);
      else       wxv4(L[0], L[1]);
      char* nb = smem + 16384 * ((s + 1) % 3);
      *(short8*)(nb + wbase) = pack8(L[0], L[1]);
    }
    asm volatile("s_waitcnt lgkmcnt(0)" ::: "memory");
    __builtin_amdgcn_s_barrier();
    asm volatile("" ::: "memory");

    if (s < 6) wbv2(bb[0], bb[1], bb[2], bb[3]);
    else       wbv0(bb[0], bb[1], bb[2], bb[3]);
    char* cur = smem + 16384 * (s % 3);
    #pragma unroll
    for (int kt4 = 0; kt4 < 4; ++kt4) {
      #pragma unroll
      for (int rt = 0; rt < 4; ++rt) {
        const short8 a = *(const short8*)(cur + (kt4 << 12) + (rt << 10)
                                          + (aO ^ (kt4 << 5)));
        mfma32(acc[rt], a, bb[kt4]);
      }
      if (w < 8 && (kt4 & 1) == 0) {
        const int schunk = kt4 + (l >> 5);
        const short8 sa = *(const short8*)(cur + (schunk << 12)
                                           + (sBase ^ ((schunk & 3) << 5)));
        const short8 sb = *(const short8*)(wscL
                            + (((2 * s + (kt4 >> 1)) << 6) + l) * 8);
        mfma16(sacc, sa, sb);
      }
    }
    if (s < 7) {
      #pragma unroll
      for (int j = 0; j < 4; ++j)
        gld4s(bb[j], wv + ((s + 1) * 4 + j) * 512);
    }
    if (s < 5) {
      f32x4 (&L)[2] = lx[(s + 3) & 1];
      const float* p = fsrc + ((s + 3) << 6);
      gld4f(L[0], p); gld4f(L[1], p + 4);
    }
  }
  asm volatile("s_nop 7\n\ts_nop 7\n\ts_nop 7" ::);  // MFMA->VALU hazard pad

  // ---- softmax over m (lane-local), waves 0..7; av[t][h] -> LDS @32K ----
  if (w < 8) {
    const int hh = l & 15;
    if (hh < 8) {
      const float sb = scoreb[hh];
      const float s0 = sacc[0] + sb, s1 = sacc[1] + sb;
      const float s2 = sacc[2] + sb, s3 = sacc[3] + sb;
      const float mx = fmaxf(fmaxf(s0, s1), fmaxf(s2, s3));
      const float e0 = __expf(s0 - mx), e1 = __expf(s1 - mx);
      const float e2 = __expf(s2 - mx), e3 = __expf(s3 - mx);
      const float inv = 1.f / (e0 + e1 + e2 + e3);
      f32x4 av; av[0] = e0 * inv; av[1] = e1 * inv; av[2] = e2 * inv; av[3] = e3 * inv;
      const int t = (w << 2) + (l >> 4);
      *(f32x4*)(smem + 32768 + (((t << 3) + hh) << 4)) = av;
    }
  }
  __syncthreads();

  // ---- blend: o_mid[t][f] = sum_m av*V + bv; scatter to frag LDS @0 ----
  {
    unsigned short* omid = (unsigned short*)(smem);
    const int ff = (w << 5) + (l & 31);
    const float bvf = in_b[1024 + ff];
    const int ktf = ff >> 4;
    const int laneL = ((l >> 3) & 1) << 5;
    const int elem = ff & 7;
    const int hq = w >> 1;                   // head of this col range
    #pragma unroll
    for (int rt = 0; rt < 4; ++rt) {
      #pragma unroll
      for (int tt = 0; tt < 4; ++tt) {
        const int t = (rt << 3) + (tt << 1) + (l >> 5);
        const f32x4 av = *(const f32x4*)(smem + 32768 + (((t << 3) + hq) << 4));
        const float o = av[0] * acc[rt][tt * 4 + 0]
                      + av[1] * acc[rt][tt * 4 + 1]
                      + av[2] * acc[rt][tt * 4 + 2]
                      + av[3] * acc[rt][tt * 4 + 3] + bvf;
        omid[((ktf << 6) + t + laneL) * 8 + elem] = f2bf(o);
      }
    }
  }
  __syncthreads();

  // ---- out-projection GEMM: [32 x 512] x Wo^T, wave owns 32 cols ----
  f32x16 oa;
  #pragma unroll
  for (int r = 0; r < 16; ++r) oa[r] = 0.f;
  const int a_off = l << 4;
  #pragma unroll 4
  for (int kt = 0; kt < 32; ++kt) {
    const short8 a = *(const short8*)(smem + (kt << 10) + a_off);
    const short8 b0 = *(const short8*)(wo + kt * 512);
    mfma32(oa, a, b0);
  }
  asm volatile("s_nop 7\n\ts_nop 7\n\ts_nop 7" ::);  // MFMA->VALU hazard pad

  // ---- LayerNorm: per-wave partial stats -> LDS @36K -> combine -> store ----
  {
    const int g0 = (w << 5) + (l & 31);
    const float ob0 = out_b[g0];
    const float gm0 = gamma[g0];
    const float bt0 = beta[g0];
    float* stats = (float*)(smem + 36864);  // [32 rows][16 waves][2]
    #pragma unroll
    for (int r = 0; r < 16; ++r) {
      const float v0 = oa[r] + ob0;
      float s = v0, qq = v0 * v0;
      s += __shfl_xor(s, 16); qq += __shfl_xor(qq, 16);
      s += __shfl_xor(s, 8);  qq += __shfl_xor(qq, 8);
      s += __shfl_xor(s, 4);  qq += __shfl_xor(qq, 4);
      s += __shfl_xor(s, 2);  qq += __shfl_xor(qq, 2);
      s += __shfl_xor(s, 1);  qq += __shfl_xor(qq, 1);
      if ((l & 31) == 0) {
        const int t = (r & 3) + ((r >> 2) << 3) + ((l >> 5) << 2);
        stats[(t << 5) + (w << 1)] = s;
        stats[(t << 5) + (w << 1) + 1] = qq;
      }
    }
    __syncthreads();
    #pragma unroll
    for (int r = 0; r < 16; ++r) {
      const int t = (r & 3) + ((r >> 2) << 3) + ((l >> 5) << 2);
      const float* st = (const float*)(smem + 36864) + (t << 5);
      float s = 0.f, qq = 0.f;
      #pragma unroll
      for (int ww = 0; ww < 8; ++ww) {
        const f32x4 u = *(const f32x4*)(st + (ww << 2));
        s += u[0] + u[2]; qq += u[1] + u[3];
      }
      const float mu = s * 0.001953125f;
      const float rs = rsqrtf(qq * 0.001953125f - mu * mu + 1e-5f);
      const float v0 = oa[r] + ob0;
      out[(size_t)(tok0 + t) * 512 + g0] = (v0 - mu) * rs * gm0 + bt0;
    }
  }
}

extern "C" void kernel_launch(void* const* d_in, const int* in_sizes, int n_in,
                              void* d_out, int out_size, void* d_ws, size_t ws_size,
                              hipStream_t stream) {
  const float* f0      = (const float*)d_in[0];
  const float* f1      = (const float*)d_in[1];
  const float* f2      = (const float*)d_in[2];
  const float* f3      = (const float*)d_in[3];
  const float* q_param = (const float*)d_in[4];
  const float* in_w    = (const float*)d_in[5];
  const float* in_b    = (const float*)d_in[6];
  const float* out_w   = (const float*)d_in[7];
  const float* out_b   = (const float*)d_in[8];
  const float* gamma   = (const float*)d_in[9];
  const float* beta    = (const float*)d_in[10];
  float* out = (float*)d_out;

  char* ws = (char*)d_ws;
  float* scoreb          = (float*)ws;                      // 64 B
  unsigned short* wscB   = (unsigned short*)(ws + 4096);    // 16 KB
  unsigned short* WvB    = (unsigned short*)(ws + 20480);   // 512 KB
  unsigned short* WoB    = (unsigned short*)(ws + 544768);  // 512 KB

  tdcp_k0<<<136, 512, 0, stream>>>(q_param, in_w, in_b, out_w,
                                   scoreb, wscB, WvB, WoB);
  tdcp_k1<<<1024, 1024, 0, stream>>>(f0, f1, f2, f3, in_b,
                                     scoreb, wscB, WvB, WoB,
                                     out_b, gamma, beta, out);
}

// Round 7
// 148.902 us; speedup vs baseline: 1.1461x; 1.1461x over previous
//
#include <hip/hip_runtime.h>
#include <hip/hip_bf16.h>

// TDCPQueryAttentionPool fused kernel for MI355X (gfx950).
// B=8, N=4096, M=4, E=512, H=8, d=64. tokens = 32768.
//
// R7: R2 structure (verified correct + tight vmcnt schedule) with the x
// global-load pattern re-laned for full 64B-segment coalescing: instr j
// reads contiguous 64B per 4-lane row group (was: 16B used per 64B segment,
// 4x transaction inflation). LDS writes become 4x ds_write_b64 (b64 4-phase
// floor, no extra conflicts). Read side / waits / epilogue identical to R2.

typedef float  f32x4  __attribute__((ext_vector_type(4)));
typedef float  f32x16 __attribute__((ext_vector_type(16)));
typedef short  short8 __attribute__((ext_vector_type(8)));
typedef unsigned int u32x2 __attribute__((ext_vector_type(2)));

__device__ __forceinline__ unsigned short f2bf(float f) {
  unsigned int x = __float_as_uint(f);
  unsigned int r = (x + 0x7fffu + ((x >> 16) & 1u)) >> 16;  // RNE
  return (unsigned short)r;
}

__device__ __forceinline__ short8 pack8(const f32x4& a, const f32x4& b) {
  unsigned int r0, r1, r2, r3;
  asm("v_cvt_pk_bf16_f32 %0, %1, %2" : "=v"(r0) : "v"(a[0]), "v"(a[1]));
  asm("v_cvt_pk_bf16_f32 %0, %1, %2" : "=v"(r1) : "v"(a[2]), "v"(a[3]));
  asm("v_cvt_pk_bf16_f32 %0, %1, %2" : "=v"(r2) : "v"(b[0]), "v"(b[1]));
  asm("v_cvt_pk_bf16_f32 %0, %1, %2" : "=v"(r3) : "v"(b[2]), "v"(b[3]));
  short8 r;
  r[0] = (short)(r0 & 0xffff); r[1] = (short)(r0 >> 16);
  r[2] = (short)(r1 & 0xffff); r[3] = (short)(r1 >> 16);
  r[4] = (short)(r2 & 0xffff); r[5] = (short)(r2 >> 16);
  r[6] = (short)(r3 & 0xffff); r[7] = (short)(r3 >> 16);
  return r;
}

__device__ __forceinline__ u32x2 pack4(const f32x4& a) {
  u32x2 r;
  asm("v_cvt_pk_bf16_f32 %0, %1, %2" : "=v"(r[0]) : "v"(a[0]), "v"(a[1]));
  asm("v_cvt_pk_bf16_f32 %0, %1, %2" : "=v"(r[1]) : "v"(a[2]), "v"(a[3]));
  return r;
}

__device__ __forceinline__ void mfma32(f32x16& c, short8 a, short8 b) {
  asm("v_mfma_f32_32x32x16_bf16 %0, %1, %2, %0" : "+v"(c) : "v"(a), "v"(b));
}
__device__ __forceinline__ void mfma16(f32x4& c, short8 a, short8 b) {
  asm("v_mfma_f32_16x16x32_bf16 %0, %1, %2, %0" : "+v"(c) : "v"(a), "v"(b));
}

__device__ __forceinline__ void gld4f(f32x4& d, const float* p) {
  asm volatile("global_load_dwordx4 %0, %1, off" : "=v"(d) : "v"(p));
}
__device__ __forceinline__ void gld4s(short8& d, const unsigned short* p) {
  asm volatile("global_load_dwordx4 %0, %1, off" : "=v"(d) : "v"(p));
}

__device__ __forceinline__ void wxv4(f32x4& a, f32x4& b, f32x4& c, f32x4& d) {
  asm volatile("s_waitcnt vmcnt(4)" : "+v"(a), "+v"(b), "+v"(c), "+v"(d));
}
__device__ __forceinline__ void wxv8(f32x4& a, f32x4& b, f32x4& c, f32x4& d) {
  asm volatile("s_waitcnt vmcnt(8)" : "+v"(a), "+v"(b), "+v"(c), "+v"(d));
}
__device__ __forceinline__ void wxv12(f32x4& a, f32x4& b, f32x4& c, f32x4& d) {
  asm volatile("s_waitcnt vmcnt(12)" : "+v"(a), "+v"(b), "+v"(c), "+v"(d));
}
__device__ __forceinline__ void wbv4(short8& a, short8& b, short8& c, short8& d,
                                     short8& e, short8& f, short8& g, short8& h) {
  asm volatile("s_waitcnt vmcnt(4)"
               : "+v"(a), "+v"(b), "+v"(c), "+v"(d),
                 "+v"(e), "+v"(f), "+v"(g), "+v"(h));
}
__device__ __forceinline__ void wbv0(short8& a, short8& b, short8& c, short8& d,
                                     short8& e, short8& f, short8& g, short8& h) {
  asm volatile("s_waitcnt vmcnt(0)"
               : "+v"(a), "+v"(b), "+v"(c), "+v"(d),
                 "+v"(e), "+v"(f), "+v"(g), "+v"(h));
}

// ---------------------------------------------------------------------------
// K0: precompute (verbatim from R1-R3; correctness-verified).
// ---------------------------------------------------------------------------
__global__ void __launch_bounds__(512) tdcp_k0(
    const float* __restrict__ q_param, const float* __restrict__ in_w,
    const float* __restrict__ in_b, const float* __restrict__ out_w,
    float* __restrict__ scoreb, unsigned short* __restrict__ wscB,
    unsigned short* __restrict__ WvB, unsigned short* __restrict__ WoB)
{
  const int tid = threadIdx.x;
  const int blk = blockIdx.x;
  if (blk < 8) {
    const int h = blk;
    __shared__ float qls[512];
    __shared__ float qs[64];
    qls[tid] = q_param[tid];
    __syncthreads();
    {
      const int io = tid >> 3, sub = tid & 7;
      const float* wrow = in_w + (size_t)(h * 64 + io) * 512;
      float v = 0.f;
      #pragma unroll 8
      for (int ee = 0; ee < 64; ++ee) {
        const int e = sub + (ee << 3);
        v += wrow[e] * qls[e];
      }
      v += __shfl_xor(v, 1); v += __shfl_xor(v, 2); v += __shfl_xor(v, 4);
      if (sub == 0) qs[io] = (v + in_b[h * 64 + io]) * 0.125f;
    }
    __syncthreads();
    {
      const int e = tid;
      const float* wk = in_w + (size_t)(512 + h * 64) * 512 + e;
      float v = 0.f;
      #pragma unroll 8
      for (int jj = 0; jj < 64; ++jj) v += qs[jj] * wk[jj * 512];
      const int s32 = e >> 5, g = (e & 31) >> 3, j = e & 7;
      wscB[((s32 << 6) + h + (g << 4)) * 8 + j] = f2bf(v);
      wscB[((s32 << 6) + (h + 8) + (g << 4)) * 8 + j] = 0;
    }
    if (tid < 64) {
      float v = qs[tid] * in_b[512 + h * 64 + tid];
      v += __shfl_xor(v, 1);  v += __shfl_xor(v, 2);  v += __shfl_xor(v, 4);
      v += __shfl_xor(v, 8);  v += __shfl_xor(v, 16); v += __shfl_xor(v, 32);
      if (tid == 0) scoreb[h] = v;
    }
    if (blk == 0 && tid >= 64 && tid < 72) scoreb[tid - 56] = 0.f;
  } else {
    const int mb = blk - 8;
    const bool isWo = mb >= 64;
    const float* src = isWo ? out_w : (in_w + (size_t)1024 * 512);
    unsigned short* dst = isWo ? WoB : WvB;
    const int slot = ((mb & 63) << 9) + tid;
    const int ct = slot >> 11, kt = (slot >> 6) & 31, ln = slot & 63;
    const float* p = src + (size_t)(ct * 32 + (ln & 31)) * 512
                         + kt * 16 + ((ln >> 5) << 3);
    const f32x4 u0 = *(const f32x4*)(p);
    const f32x4 u1 = *(const f32x4*)(p + 4);
    short8 rr;
    rr[0] = (short)f2bf(u0[0]); rr[1] = (short)f2bf(u0[1]);
    rr[2] = (short)f2bf(u0[2]); rr[3] = (short)f2bf(u0[3]);
    rr[4] = (short)f2bf(u1[0]); rr[5] = (short)f2bf(u1[1]);
    rr[6] = (short)f2bf(u1[2]); rr[7] = (short)f2bf(u1[3]);
    *(short8*)(dst + slot * 8) = rr;
  }
}

// ---------------------------------------------------------------------------
// K1: fused attention-pool, counted-vmcnt pipeline (R2 structure).
// LDS map: [0,48K) three 16K x-buffers; [48K,64K) wsc frags.
// After main loop: omid [0,32K), av [32K,36K), stats [36K,38K).
// ---------------------------------------------------------------------------
__global__ void __launch_bounds__(512, 2) tdcp_k1(
    const float* __restrict__ f0, const float* __restrict__ f1,
    const float* __restrict__ f2, const float* __restrict__ f3,
    const float* __restrict__ in_b,
    const float* __restrict__ scoreb, const unsigned short* __restrict__ wscB,
    const unsigned short* __restrict__ WvB, const unsigned short* __restrict__ WoB,
    const float* __restrict__ out_b, const float* __restrict__ gamma,
    const float* __restrict__ beta, float* __restrict__ out)
{
  __shared__ __align__(16) char smem[65536];
  const int tid = threadIdx.x;
  const int w = tid >> 6;         // wave 0..7: owns output cols [64w,64w+64)
  const int l = tid & 63;
  const int tok0 = blockIdx.x << 5;

  // ---- wsc -> LDS (16 KB) ----
  {
    const f32x4* wsrc = (const f32x4*)wscB;
    f32x4* wdst = (f32x4*)(smem + 49152);
    wdst[tid * 2] = wsrc[tid * 2];
    wdst[tid * 2 + 1] = wsrc[tid * 2 + 1];
  }

  // ---- staging map (R7): row sr = t*4+m (0..127), c = tid&3 ----
  // load instr j (j=0..3): lane reads 16B at row sr, float off 4c + 16j
  //   -> per instr, each 4-lane row group covers contiguous 64B.  Thread
  //   holds 4 strided 4-float groups; each packs to one 8B LDS unit.
  const int sr = tid >> 2;
  const int c = tid & 3;
  const int sm = sr & 3;
  const int stk = sr >> 2;
  const float* fsrc = (sm == 0 ? f0 : sm == 1 ? f1 : sm == 2 ? f2 : f3)
                      + (size_t)(tok0 + stk) * 512 + (c << 2);
  // LDS write offsets per j (same layout as R2 read side):
  //   (j<<12) + ((sr>>5)<<10) + ((c>>1)<<9) + (((sr&31)<<4) ^ (j<<5)) + ((c&1)<<3)
  int wj[4];
  #pragma unroll
  for (int j = 0; j < 4; ++j)
    wj[j] = (j << 12) + ((sr >> 5) << 10) + ((c >> 1) << 9)
          + ((((sr & 31) << 4)) ^ (j << 5)) + ((c & 1) << 3);

  // ---- fragment-read bases (unchanged from R2) ----
  const int aO = ((l >> 5) << 9) + ((l & 31) << 4);
  const int sBase = ((w >> 1) << 10) + (((l >> 4) & 1) << 9)
                  + ((((w & 1) << 4) | (l & 15)) << 4);
  const int ct0 = w << 1;
  const unsigned short* wv0 = WvB + (((ct0 * 32) << 6) + l) * 8;
  const unsigned short* wv1 = WvB + ((((ct0 + 1) * 32) << 6) + l) * 8;
  const unsigned short* wscL = (const unsigned short*)(smem + 49152);

  f32x16 acc[4][2];
  f32x4 sacc;
  #pragma unroll
  for (int i = 0; i < 4; ++i)
    #pragma unroll
    for (int cc = 0; cc < 2; ++cc)
      #pragma unroll
      for (int r = 0; r < 16; ++r) acc[i][cc][r] = 0.f;
  sacc[0] = sacc[1] = sacc[2] = sacc[3] = 0.f;

  f32x4 lx[2][4];
  short8 bb[2][8];

  // ---- prologue: L0,L1 issue; pack buf0; B0 issue; L2 issue; barrier ----
  gld4f(lx[0][0], fsrc);      gld4f(lx[0][1], fsrc + 16);
  gld4f(lx[0][2], fsrc + 32); gld4f(lx[0][3], fsrc + 48);
  gld4f(lx[1][0], fsrc + 64); gld4f(lx[1][1], fsrc + 80);
  gld4f(lx[1][2], fsrc + 96); gld4f(lx[1][3], fsrc + 112);
  wxv4(lx[0][0], lx[0][1], lx[0][2], lx[0][3]);
  #pragma unroll
  for (int j = 0; j < 4; ++j)
    *(u32x2*)(smem + wj[j]) = pack4(lx[0][j]);
  #pragma unroll
  for (int j = 0; j < 4; ++j) {
    gld4s(bb[0][2 * j],     wv0 + j * 512);
    gld4s(bb[0][2 * j + 1], wv1 + j * 512);
  }
  gld4f(lx[0][0], fsrc + 128); gld4f(lx[0][1], fsrc + 144);
  gld4f(lx[0][2], fsrc + 160); gld4f(lx[0][3], fsrc + 176);
  asm volatile("s_waitcnt lgkmcnt(0)" ::: "memory");
  __builtin_amdgcn_s_barrier();
  asm volatile("" ::: "memory");

  // ---- main loop: 8 steps of 64 e-elements (R2-verified schedule) ----
  #pragma unroll
  for (int s = 0; s < 8; ++s) {
    if (s < 7) {
      f32x4 (&L)[4] = lx[(s + 1) & 1];
      if (s < 6) wxv12(L[0], L[1], L[2], L[3]);
      else       wxv8(L[0], L[1], L[2], L[3]);
      char* nb = smem + 16384 * ((s + 1) % 3);
      #pragma unroll
      for (int j = 0; j < 4; ++j)
        *(u32x2*)(nb + wj[j]) = pack4(L[j]);
    }
    asm volatile("s_waitcnt lgkmcnt(0)" ::: "memory");
    __builtin_amdgcn_s_barrier();
    asm volatile("" ::: "memory");

    short8 (&b)[8] = bb[s & 1];
    if (s < 6) wbv4(b[0], b[1], b[2], b[3], b[4], b[5], b[6], b[7]);
    else       wbv0(b[0], b[1], b[2], b[3], b[4], b[5], b[6], b[7]);
    char* cur = smem + 16384 * (s % 3);
    const short8 sb0 = *(const short8*)(wscL + (((2 * s) << 6) + l) * 8);
    const short8 sb1 = *(const short8*)(wscL + (((2 * s + 1) << 6) + l) * 8);
    #pragma unroll
    for (int kt4 = 0; kt4 < 4; ++kt4) {
      #pragma unroll
      for (int rt = 0; rt < 4; ++rt) {
        const short8 a = *(const short8*)(cur + (kt4 << 12) + (rt << 10)
                                          + (aO ^ (kt4 << 5)));
        mfma32(acc[rt][0], a, b[kt4 * 2]);
        mfma32(acc[rt][1], a, b[kt4 * 2 + 1]);
      }
      if ((kt4 & 1) == 0) {
        const int schunk = kt4 + (l >> 5);
        const short8 sa = *(const short8*)(cur + (schunk << 12)
                                           + (sBase ^ ((schunk & 3) << 5)));
        mfma16(sacc, sa, (kt4 == 0) ? sb0 : sb1);
      }
    }
    if (s < 7) {
      short8 (&nbf)[8] = bb[(s + 1) & 1];
      #pragma unroll
      for (int j = 0; j < 4; ++j) {
        gld4s(nbf[2 * j],     wv0 + ((s + 1) * 4 + j) * 512);
        gld4s(nbf[2 * j + 1], wv1 + ((s + 1) * 4 + j) * 512);
      }
    }
    if (s < 5) {
      f32x4 (&L)[4] = lx[(s + 3) & 1];
      const float* p = fsrc + ((s + 3) << 6);
      gld4f(L[0], p); gld4f(L[1], p + 16); gld4f(L[2], p + 32); gld4f(L[3], p + 48);
    }
  }
  asm volatile("s_nop 7\n\ts_nop 7\n\ts_nop 7" ::);  // MFMA->VALU hazard pad

  // ---- softmax over m (lane-local), write av[t][h] to LDS @32K ----
  {
    const int hh = l & 15;
    if (hh < 8) {
      const float sb = scoreb[hh];
      const float s0 = sacc[0] + sb, s1 = sacc[1] + sb;
      const float s2 = sacc[2] + sb, s3 = sacc[3] + sb;
      const float mx = fmaxf(fmaxf(s0, s1), fmaxf(s2, s3));
      const float e0 = __expf(s0 - mx), e1 = __expf(s1 - mx);
      const float e2 = __expf(s2 - mx), e3 = __expf(s3 - mx);
      const float inv = 1.f / (e0 + e1 + e2 + e3);
      f32x4 av; av[0] = e0 * inv; av[1] = e1 * inv; av[2] = e2 * inv; av[3] = e3 * inv;
      const int t = (w << 2) + (l >> 4);
      *(f32x4*)(smem + 32768 + (((t << 3) + hh) << 4)) = av;
    }
  }
  __syncthreads();

  // ---- blend: o_mid[t][f] = sum_m av*V + bv; scatter to frag LDS @0 ----
  {
    unsigned short* omid = (unsigned short*)(smem);
    #pragma unroll
    for (int c2 = 0; c2 < 2; ++c2) {
      const int ff = ((ct0 + c2) << 5) + (l & 31);
      const float bvf = in_b[1024 + ff];
      const int ktf = ff >> 4;
      const int laneL = ((l >> 3) & 1) << 5;
      const int elem = ff & 7;
      #pragma unroll
      for (int rt = 0; rt < 4; ++rt) {
        #pragma unroll
        for (int tt = 0; tt < 4; ++tt) {
          const int t = (rt << 3) + (tt << 1) + (l >> 5);
          const f32x4 av = *(const f32x4*)(smem + 32768 + (((t << 3) + w) << 4));
          const float o = av[0] * acc[rt][c2][tt * 4 + 0]
                        + av[1] * acc[rt][c2][tt * 4 + 1]
                        + av[2] * acc[rt][c2][tt * 4 + 2]
                        + av[3] * acc[rt][c2][tt * 4 + 3] + bvf;
          omid[((ktf << 6) + t + laneL) * 8 + elem] = f2bf(o);
        }
      }
    }
  }
  __syncthreads();

  // ---- out-projection GEMM: [32 x 512] x Wo^T (R2-verified, unroll 4) ----
  f32x16 oa0, oa1;
  #pragma unroll
  for (int r = 0; r < 16; ++r) { oa0[r] = 0.f; oa1[r] = 0.f; }
  const unsigned short* wo0 = WoB + (((ct0 * 32) << 6) + l) * 8;
  const unsigned short* wo1 = WoB + ((((ct0 + 1) * 32) << 6) + l) * 8;
  const int a_off = l << 4;
  #pragma unroll 4
  for (int kt = 0; kt < 32; ++kt) {
    const short8 a = *(const short8*)(smem + (kt << 10) + a_off);
    mfma32(oa0, a, *(const short8*)(wo0 + kt * 512));
    mfma32(oa1, a, *(const short8*)(wo1 + kt * 512));
  }
  asm volatile("s_nop 7\n\ts_nop 7\n\ts_nop 7" ::);  // MFMA->VALU hazard pad

  // ---- LayerNorm: per-wave partial stats -> LDS @36K -> combine -> store ----
  {
    const int g0 = (ct0 << 5) + (l & 31);
    const int g1 = g0 + 32;
    const float ob0 = out_b[g0], ob1 = out_b[g1];
    const float gm0 = gamma[g0], gm1 = gamma[g1];
    const float bt0 = beta[g0],  bt1 = beta[g1];
    float* stats = (float*)(smem + 36864);  // [32][8 waves][2]
    #pragma unroll
    for (int r = 0; r < 16; ++r) {
      const float v0 = oa0[r] + ob0, v1 = oa1[r] + ob1;
      float s = v0 + v1, qq = v0 * v0 + v1 * v1;
      s += __shfl_xor(s, 16); qq += __shfl_xor(qq, 16);
      s += __shfl_xor(s, 8);  qq += __shfl_xor(qq, 8);
      s += __shfl_xor(s, 4);  qq += __shfl_xor(qq, 4);
      s += __shfl_xor(s, 2);  qq += __shfl_xor(qq, 2);
      s += __shfl_xor(s, 1);  qq += __shfl_xor(qq, 1);
      if ((l & 31) == 0) {
        const int t = (r & 3) + ((r >> 2) << 3) + ((l >> 5) << 2);
        stats[(t << 4) + (w << 1)] = s;
        stats[(t << 4) + (w << 1) + 1] = qq;
      }
    }
    __syncthreads();
    #pragma unroll
    for (int r = 0; r < 16; ++r) {
      const int t = (r & 3) + ((r >> 2) << 3) + ((l >> 5) << 2);
      const float* st = stats + (t << 4);
      float s = 0.f, qq = 0.f;
      #pragma unroll
      for (int ww = 0; ww < 8; ++ww) { s += st[2 * ww]; qq += st[2 * ww + 1]; }
      const float mu = s * 0.001953125f;
      const float rs = rsqrtf(qq * 0.001953125f - mu * mu + 1e-5f);
      const float v0 = oa0[r] + ob0, v1 = oa1[r] + ob1;
      float* op = out + (size_t)(tok0 + t) * 512;
      op[g0] = (v0 - mu) * rs * gm0 + bt0;
      op[g1] = (v1 - mu) * rs * gm1 + bt1;
    }
  }
}

extern "C" void kernel_launch(void* const* d_in, const int* in_sizes, int n_in,
                              void* d_out, int out_size, void* d_ws, size_t ws_size,
                              hipStream_t stream) {
  const float* f0      = (const float*)d_in[0];
  const float* f1      = (const float*)d_in[1];
  const float* f2      = (const float*)d_in[2];
  const float* f3      = (const float*)d_in[3];
  const float* q_param = (const float*)d_in[4];
  const float* in_w    = (const float*)d_in[5];
  const float* in_b    = (const float*)d_in[6];
  const float* out_w   = (const float*)d_in[7];
  const float* out_b   = (const float*)d_in[8];
  const float* gamma   = (const float*)d_in[9];
  const float* beta    = (const float*)d_in[10];
  float* out = (float*)d_out;

  char* ws = (char*)d_ws;
  float* scoreb          = (float*)ws;                      // 64 B
  unsigned short* wscB   = (unsigned short*)(ws + 4096);    // 16 KB
  unsigned short* WvB    = (unsigned short*)(ws + 20480);   // 512 KB
  unsigned short* WoB    = (unsigned short*)(ws + 544768);  // 512 KB

  tdcp_k0<<<136, 512, 0, stream>>>(q_param, in_w, in_b, out_w,
                                   scoreb, wscB, WvB, WoB);
  tdcp_k1<<<1024, 512, 0, stream>>>(f0, f1, f2, f3, in_b,
                                    scoreb, wscB, WvB, WoB,
                                    out_b, gamma, beta, out);
}